// Round 12
// baseline (28.367 us; speedup 1.0000x reference)
//
#include <hip/hip_runtime.h>

// Problem constants (match setup_inputs)
#define BB   2
#define CC   3
#define HH   192
#define WW   192
#define LL   19
#define PADR 9
#define HP   (HH + 2 * PADR)   // 210
#define WP   (WW + 2 * PADR)   // 210
#define HWN  (HH * WW)         // 36864
#define TAPS (LL * LL)         // 361

#define PIXB  32                 // pixels per block
#define NG    (HWN / PIXB)       // 1152 groups per kb
#define TCOLS (PIXB + LL - 1)    // 50 tile cols (float4)
#define IF4   (LL * TCOLS)       // 950 float4 of image tile per block

#define GLOAD_LDS16(g, l)                                                     \
    __builtin_amdgcn_global_load_lds(                                         \
        (const __attribute__((address_space(1))) void*)(g),                   \
        (__attribute__((address_space(3))) void*)(l), 16, 0, 0)

// DPP row_shr add step: a[i] += a[i-N] within each 16-lane row (OOB -> 0).
// CTRL must be a compile-time constant (frontend requirement), hence template.
template <int CTRL>
__device__ __forceinline__ float dpp_add(float a) {
    int t = __builtin_amdgcn_update_dpp(0, __float_as_int(a), CTRL, 0xf, 0xf,
                                        true);
    return a + __int_as_float(t);
}

// Reflect-pad + rearrange image into (kb, HP, WP, float4) where component j
// holds channel-slot n = kb + BB*j (n = b*CC + c ordering of the reference).
__global__ __launch_bounds__(256) void pad_rearrange(
    const float* __restrict__ x, float4* __restrict__ img) {
    int idx = blockIdx.x * blockDim.x + threadIdx.x;
    const int total = BB * HP * WP;
    if (idx >= total) return;
    int xw  = idx % WP;
    int tmp = idx / WP;
    int y   = tmp % HP;
    int kb  = tmp / HP;
    int oy = y - PADR;
    oy = oy < 0 ? -oy : (oy >= HH ? 2 * HH - 2 - oy : oy);
    int ox = xw - PADR;
    ox = ox < 0 ? -ox : (ox >= WW ? 2 * WW - 2 - ox : ox);
    float v[3];
#pragma unroll
    for (int j = 0; j < 3; ++j) {
        int n = kb + BB * j;  // n = b*CC + c, with n % BB == kb
        v[j] = x[((size_t)n * HH + oy) * WW + ox];
    }
    img[idx] = make_float4(v[0], v[1], v[2], 0.0f);
}

// 512-thread block = 32 consecutive same-row pixels of one kb.
// Image tile (19x50 float4, 15.2 KB) staged via 2 rounds of 16B
// global_load_lds. Kernel taps stream global->register (coalesced 64B per
// 16-lane group). Tap->tile offset incremental in registers. Reduce via
// DPP row_shr adds (VALU pipe, not DS). Lane q==15 holds the sum.
__global__ __launch_bounds__(512) void sv_blur32(
    const float* __restrict__ kern, const float4* __restrict__ img,
    float* __restrict__ out) {
    __shared__ float4 tile[1024];    // 2 rounds * 512 (slots >= 950 unused)

    int bx  = blockIdx.x;
    int kb  = bx / NG;
    int grp = bx % NG;
    int p0  = grp * PIXB;
    int h   = p0 / WW, w0 = p0 % WW;   // w0 multiple of 32: no row crossing
    int tid = threadIdx.x;
    int wv  = tid >> 6;

    // ---- stage image swath rows h..h+18, cols w0..w0+49 ----
    const float4* isrc = img + ((size_t)kb * HP + h) * WP + w0;
#pragma unroll
    for (int r = 0; r < 2; ++r) {
        int li = (r << 9) + tid;
        int si = li < IF4 ? li : IF4 - 1;
        int rr = si / TCOLS, cc = si % TCOLS;
        GLOAD_LDS16(isrc + (size_t)rr * WP + cc,
                    (char*)tile + (size_t)(((r << 9) + (wv << 6)) << 4));
    }
    __syncthreads();

    // ---- compute: 16 lanes per pixel, kv from global ----
    int pp = tid >> 4;             // pixel 0..31
    int q  = tid & 15;             // lane in 16-group
    int p  = p0 + pp;
    const float*  kl = kern + (size_t)(kb * HWN + p) * TAPS + q;
    const float4* tb = tile + pp;

    // incremental tap coords for t = q + 16j: kj=t%19, ioff=(t/19)*50+kj
    int kj   = q;          // q <= 15 < 19
    int ioff = q;
    float a0 = 0.f, a1 = 0.f, a2 = 0.f;
#pragma unroll
    for (int j = 0; j < 22; ++j) {     // t = q..q+336: always < 361
        float  kv = kl[j << 4];        // base+q + 16j floats (imm offset)
        float4 iv = tb[ioff];
        a0 = fmaf(kv, iv.x, a0);
        a1 = fmaf(kv, iv.y, a1);
        a2 = fmaf(kv, iv.z, a2);
        // t += 16: kj+16 wraps past 19 iff kj >= 3
        bool wrap = kj >= 3;
        ioff += wrap ? 47 : 16;        // +50-3 on row wrap, else +16
        kj    = wrap ? kj - 3 : kj + 16;
    }
    if (q < 9) {                        // tail: t = q+352 valid for q < 9
        float  kv = kl[22 << 4];
        float4 iv = tb[ioff];
        a0 = fmaf(kv, iv.x, a0);
        a1 = fmaf(kv, iv.y, a1);
        a2 = fmaf(kv, iv.z, a2);
    }

    // ---- 16-lane reduce on the VALU pipe (DPP row_shr adds) ----
    a0 = dpp_add<0x111>(a0); a1 = dpp_add<0x111>(a1); a2 = dpp_add<0x111>(a2);
    a0 = dpp_add<0x112>(a0); a1 = dpp_add<0x112>(a1); a2 = dpp_add<0x112>(a2);
    a0 = dpp_add<0x114>(a0); a1 = dpp_add<0x114>(a1); a2 = dpp_add<0x114>(a2);
    a0 = dpp_add<0x118>(a0); a1 = dpp_add<0x118>(a1); a2 = dpp_add<0x118>(a2);

    if (q == 15) {                     // lane 15 holds the full 16-lane sum
        out[(size_t)(kb + 0 * BB) * HWN + p] = a0;
        out[(size_t)(kb + 1 * BB) * HWN + p] = a1;
        out[(size_t)(kb + 2 * BB) * HWN + p] = a2;
    }
}

// Fallback (no workspace): inline reflect, 3 scalar image loads per tap.
__global__ __launch_bounds__(256) void sv_blur_nows(
    const float* __restrict__ kern, const float* __restrict__ x,
    float* __restrict__ out) {
    int wid  = (blockIdx.x * blockDim.x + threadIdx.x) >> 6;
    int lane = threadIdx.x & 63;
    int p  = wid % HWN;
    int kb = wid / HWN;
    int h = p / WW, w = p % WW;
    const float* kbase = kern + (size_t)(kb * HWN + p) * TAPS;
    float a[3] = {0.f, 0.f, 0.f};
#pragma unroll
    for (int it = 0; it < 6; ++it) {
        int t = lane + 64 * it;
        if (t < TAPS) {
            float kv = kbase[t];
            int ki = t / LL, kj = t % LL;
            int oy = h + ki - PADR;
            oy = oy < 0 ? -oy : (oy >= HH ? 2 * HH - 2 - oy : oy);
            int ox = w + kj - PADR;
            ox = ox < 0 ? -ox : (ox >= WW ? 2 * WW - 2 - ox : ox);
#pragma unroll
            for (int j = 0; j < 3; ++j) {
                int n = kb + BB * j;
                a[j] = fmaf(kv, x[((size_t)n * HH + oy) * WW + ox], a[j]);
            }
        }
    }
#pragma unroll
    for (int m = 32; m; m >>= 1) {
        a[0] += __shfl_xor(a[0], m, 64);
        a[1] += __shfl_xor(a[1], m, 64);
        a[2] += __shfl_xor(a[2], m, 64);
    }
    if (lane == 0) {
#pragma unroll
        for (int j = 0; j < 3; ++j)
            out[(size_t)(kb + j * BB) * HWN + p] = a[j];
    }
}

extern "C" void kernel_launch(void* const* d_in, const int* in_sizes, int n_in,
                              void* d_out, int out_size, void* d_ws, size_t ws_size,
                              hipStream_t stream) {
    const float* x    = (const float*)d_in[0];
    const float* kern = (const float*)d_in[1];
    float*       out  = (float*)d_out;

    const size_t need = (size_t)BB * HP * WP * sizeof(float4);  // ~1.41 MB

    if (ws_size >= need) {
        float4* img = (float4*)d_ws;
        const int ptotal = BB * HP * WP;
        pad_rearrange<<<(ptotal + 255) / 256, 256, 0, stream>>>(x, img);
        sv_blur32<<<BB * NG, 512, 0, stream>>>(kern, img, out);
    } else {
        const int nwaves  = BB * HWN;
        const int nblocks = nwaves / 4;
        sv_blur_nows<<<nblocks, 256, 0, stream>>>(kern, x, out);
    }
}

// Round 13
// 23.645 us; speedup vs baseline: 1.1997x; 1.1997x over previous
//
#include <hip/hip_runtime.h>

// Problem constants (match setup_inputs)
#define BB   2
#define CC   3
#define HH   192
#define WW   192
#define LL   19
#define PADR 9
#define HWN  (HH * WW)          // 36864
#define TAPS (LL * LL)          // 361

#define PIXB  32                 // pixels per block
#define NG    (HWN / PIXB)       // 1152 groups per kb
#define TCOLS (PIXB + LL - 1)    // 50 tile cols (float4)
#define IF4   (LL * TCOLS)       // 950 float4 of image tile per block

// DPP row_shr add step: a[i] += a[i-N] within each 16-lane row (OOB -> 0).
template <int CTRL>
__device__ __forceinline__ float dpp_add(float a) {
    int t = __builtin_amdgcn_update_dpp(0, __float_as_int(a), CTRL, 0xf, 0xf,
                                        true);
    return a + __int_as_float(t);
}

__device__ __forceinline__ int reflect_h(int y) {
    return y < 0 ? -y : (y >= HH ? 2 * HH - 2 - y : y);
}
__device__ __forceinline__ int reflect_w(int xq) {
    return xq < 0 ? -xq : (xq >= WW ? 2 * WW - 2 - xq : xq);
}

// Single fused dispatch. 512-thread block = 32 consecutive same-row pixels of
// one kb. Staging: each thread builds <=2 of the 950 packed tile float4s
// directly from x (3 coalesced channel dword loads at reflected addresses,
// channels j=0..2 -> slot n=kb+2j, + one ds_write_b128). x is 0.88 MB ->
// L2-resident. Compute loop identical to the verified R11 kernel: kv
// global->register (coalesced 64B per 16-lane group), iv ds_read_b128 with
// incremental tap->tile offset, DPP reduce on the VALU pipe.
__global__ __launch_bounds__(512) void sv_blur_f32(
    const float* __restrict__ x, const float* __restrict__ kern,
    float* __restrict__ out) {
    __shared__ float4 tile[IF4];     // 950 float4 = 15.2 KB

    int bx  = blockIdx.x;
    int kb  = bx / NG;
    int grp = bx % NG;
    int p0  = grp * PIXB;
    int h   = p0 / WW, w0 = p0 % WW;   // w0 multiple of 32: no row crossing
    int tid = threadIdx.x;

    // ---- stage packed reflected tile: rows h-9..h+9, cols w0-9..w0+40 ----
#pragma unroll
    for (int r = 0; r < 2; ++r) {
        int s = (r << 9) + tid;
        if (s < IF4) {
            int pr = s / TCOLS, pc = s % TCOLS;
            int oy = reflect_h(h + pr - PADR);
            int ox = reflect_w(w0 + pc - PADR);
            size_t base = (size_t)oy * WW + ox;
            float v0 = x[(size_t)(kb + 0 * BB) * HWN + base];
            float v1 = x[(size_t)(kb + 1 * BB) * HWN + base];
            float v2 = x[(size_t)(kb + 2 * BB) * HWN + base];
            tile[s] = make_float4(v0, v1, v2, 0.0f);
        }
    }
    __syncthreads();

    // ---- compute: 16 lanes per pixel, kv from global (R11-verified) ----
    int pp = tid >> 4;             // pixel 0..31
    int q  = tid & 15;             // lane in 16-group
    int p  = p0 + pp;
    const float*  kl = kern + (size_t)(kb * HWN + p) * TAPS + q;
    const float4* tb = tile + pp;

    // incremental tap coords for t = q + 16j: kj=t%19, ioff=(t/19)*50+kj
    int kj   = q;          // q <= 15 < 19
    int ioff = q;
    float a0 = 0.f, a1 = 0.f, a2 = 0.f;
#pragma unroll
    for (int j = 0; j < 22; ++j) {     // t = q..q+336: always < 361
        float  kv = kl[j << 4];        // base+q + 16j floats (imm offset)
        float4 iv = tb[ioff];
        a0 = fmaf(kv, iv.x, a0);
        a1 = fmaf(kv, iv.y, a1);
        a2 = fmaf(kv, iv.z, a2);
        // t += 16: kj+16 wraps past 19 iff kj >= 3
        bool wrap = kj >= 3;
        ioff += wrap ? 47 : 16;        // +50-3 on row wrap, else +16
        kj    = wrap ? kj - 3 : kj + 16;
    }
    if (q < 9) {                        // tail: t = q+352 valid for q < 9
        float  kv = kl[22 << 4];
        float4 iv = tb[ioff];
        a0 = fmaf(kv, iv.x, a0);
        a1 = fmaf(kv, iv.y, a1);
        a2 = fmaf(kv, iv.z, a2);
    }

    // ---- 16-lane reduce on the VALU pipe (DPP row_shr adds) ----
    a0 = dpp_add<0x111>(a0); a1 = dpp_add<0x111>(a1); a2 = dpp_add<0x111>(a2);
    a0 = dpp_add<0x112>(a0); a1 = dpp_add<0x112>(a1); a2 = dpp_add<0x112>(a2);
    a0 = dpp_add<0x114>(a0); a1 = dpp_add<0x114>(a1); a2 = dpp_add<0x114>(a2);
    a0 = dpp_add<0x118>(a0); a1 = dpp_add<0x118>(a1); a2 = dpp_add<0x118>(a2);

    if (q == 15) {                     // lane 15 holds the full 16-lane sum
        out[(size_t)(kb + 0 * BB) * HWN + p] = a0;
        out[(size_t)(kb + 1 * BB) * HWN + p] = a1;
        out[(size_t)(kb + 2 * BB) * HWN + p] = a2;
    }
}

extern "C" void kernel_launch(void* const* d_in, const int* in_sizes, int n_in,
                              void* d_out, int out_size, void* d_ws, size_t ws_size,
                              hipStream_t stream) {
    const float* x    = (const float*)d_in[0];
    const float* kern = (const float*)d_in[1];
    float*       out  = (float*)d_out;
    sv_blur_f32<<<BB * NG, 512, 0, stream>>>(x, kern, out);
}